// Round 1
// baseline (152.929 us; speedup 1.0000x reference)
//
#include <hip/hip_runtime.h>
#include <hip/hip_bf16.h>

#define N_NODES 100000
#define N_EDGES 500000
#define EDIM 128

using bf16x8 = __attribute__((ext_vector_type(8))) __bf16;
using f32x4  = __attribute__((ext_vector_type(4))) float;

// ---- prep 1: z f32 -> bf16 (12.8M elems, 8/thread) ----
__global__ void cvt_z_kernel(const float* __restrict__ z, __bf16* __restrict__ zb) {
    int i = blockIdx.x * blockDim.x + threadIdx.x;   // 1.6M threads exactly
    const float4* p = (const float4*)z + (size_t)i * 2;
    float4 a = p[0], b = p[1];
    bf16x8 o;
    o[0] = (__bf16)a.x; o[1] = (__bf16)a.y; o[2] = (__bf16)a.z; o[3] = (__bf16)a.w;
    o[4] = (__bf16)b.x; o[5] = (__bf16)b.y; o[6] = (__bf16)b.z; o[7] = (__bf16)b.w;
    ((bf16x8*)zb)[i] = o;
}

// ---- prep 2: W1 [256][128] f32 -> bf16 in MFMA B-fragment order ----
// fragment (kt,nt): 64 lanes x 8 elems; lane holds B[k=kt*32+(l>>4)*8+i][n=nt*16+(l&15)]
__global__ void cvt_w1_kernel(const float* __restrict__ W1, __bf16* __restrict__ w1f) {
    int t = blockIdx.x * blockDim.x + threadIdx.x;   // 0..4095
    int lane = t & 63, frag = t >> 6;
    int kt = frag >> 3, nt = frag & 7;
    int k0 = kt * 32 + (lane >> 4) * 8;
    int n  = nt * 16 + (lane & 15);
    bf16x8 o;
#pragma unroll
    for (int i = 0; i < 8; i++) o[i] = (__bf16)W1[(k0 + i) * 128 + n];
    ((bf16x8*)w1f)[t] = o;
}

// ---- main: per block 256 edges (4 waves x 64), W1 in LDS fragment-ordered ----
__global__ __launch_bounds__(256, 2) void decode_kernel(
    const __bf16* __restrict__ zb, const __bf16* __restrict__ w1f,
    const int* __restrict__ ei, const float* __restrict__ b1,
    const float* __restrict__ W2, const float* __restrict__ b2,
    float* __restrict__ out)
{
    __shared__ __bf16 sW[64 * 512];  // 64 KB, fragment-ordered (conflict-free reads)
    {
        const uint4* src = (const uint4*)w1f;
        uint4* dst = (uint4*)sW;
#pragma unroll
        for (int i = 0; i < 16; i++)
            dst[threadIdx.x + 256 * i] = src[threadIdx.x + 256 * i];
    }
    __syncthreads();

    const int lane = threadIdx.x & 63;
    const int wave = threadIdx.x >> 6;
    const int l15 = lane & 15, l4 = lane >> 4;
    const long long ebase = (long long)blockIdx.x * 256 + wave * 64;

    // per-lane row pointers for the 4 M-tiles (lane l15 owns edge row l15 of each tile)
    const __bf16* aptr[4][2];
#pragma unroll
    for (int mt = 0; mt < 4; mt++) {
        long long e = ebase + mt * 16 + l15;
        if (e >= N_EDGES) e = N_EDGES - 1;          // clamp for tail (store predicated later)
        int si = ei[e];
        int di = ei[N_EDGES + e];
        aptr[mt][0] = zb + (size_t)si * EDIM + l4 * 8;
        aptr[mt][1] = zb + (size_t)di * EDIM + l4 * 8;
    }

    const f32x4 zero = {0.f, 0.f, 0.f, 0.f};
    f32x4 acc[4][8];
#pragma unroll
    for (int mt = 0; mt < 4; mt++)
#pragma unroll
        for (int nt = 0; nt < 8; nt++) acc[mt][nt] = zero;

#pragma unroll
    for (int kt = 0; kt < 8; kt++) {
        bf16x8 bfr[8];
#pragma unroll
        for (int nt = 0; nt < 8; nt++)
            bfr[nt] = *(const bf16x8*)&sW[(kt * 8 + nt) * 512 + lane * 8];
        const int half = kt >> 2;          // 0: src embedding, 1: dst embedding
        const int ko   = (kt & 3) * 32;    // k offset within that embedding
#pragma unroll
        for (int mt = 0; mt < 4; mt++) {
            bf16x8 a = *(const bf16x8*)(aptr[mt][half] + ko);
#pragma unroll
            for (int nt = 0; nt < 8; nt++)
                acc[mt][nt] = __builtin_amdgcn_mfma_f32_16x16x32_bf16(a, bfr[nt], acc[mt][nt], 0, 0, 0);
        }
    }

    // epilogue: h = relu(acc + b1); out = h . W2 + b2
    float b1v[8], w2v[8];
#pragma unroll
    for (int nt = 0; nt < 8; nt++) {
        int c = nt * 16 + l15;
        b1v[nt] = b1[c];
        w2v[nt] = W2[c];
    }
    const float bias2 = b2[0];

#pragma unroll
    for (int mt = 0; mt < 4; mt++) {
#pragma unroll
        for (int j = 0; j < 4; j++) {
            float p = 0.f;
#pragma unroll
            for (int nt = 0; nt < 8; nt++)
                p += fmaxf(acc[mt][nt][j] + b1v[nt], 0.f) * w2v[nt];
            p += __shfl_xor(p, 1, 64);
            p += __shfl_xor(p, 2, 64);
            p += __shfl_xor(p, 4, 64);
            p += __shfl_xor(p, 8, 64);
            long long e = ebase + mt * 16 + l4 * 4 + j;
            if (l15 == 0 && e < N_EDGES) out[e] = p + bias2;
        }
    }
}

extern "C" void kernel_launch(void* const* d_in, const int* in_sizes, int n_in,
                              void* d_out, int out_size, void* d_ws, size_t ws_size,
                              hipStream_t stream) {
    const float* z  = (const float*)d_in[0];
    const int*   ei = (const int*)d_in[1];   // [2, N_EDGES] int32
    const float* W1 = (const float*)d_in[2];
    const float* b1 = (const float*)d_in[3];
    const float* W2 = (const float*)d_in[4];
    const float* b2 = (const float*)d_in[5];
    float* out = (float*)d_out;

    __bf16* zb  = (__bf16*)d_ws;                                        // 25.6 MB
    __bf16* w1f = (__bf16*)((char*)d_ws + (size_t)N_NODES * EDIM * 2);  // 64 KB

    cvt_z_kernel<<<(N_NODES * EDIM / 8) / 256, 256, 0, stream>>>(z, zb);
    cvt_w1_kernel<<<16, 256, 0, stream>>>(W1, w1f);
    decode_kernel<<<(N_EDGES + 255) / 256, 256, 0, stream>>>(zb, w1f, ei, b1, W2, b2, out);
}